// Round 1
// baseline (1932.949 us; speedup 1.0000x reference)
//
#include <hip/hip_runtime.h>
#include <hip/hip_bf16.h>

// Problem constants
constexpr int NQ  = 100;
constexpr int NT  = 197;
constexpr int BSZ = 128;
constexpr int EMB = 768;
constexpr int NHD = 12;
constexpr int HDD = 64;
constexpr int COLS = BSZ * EMB;          // 98304
constexpr int M_Q  = NQ * BSZ;           // 12800
constexpr int M_KV = NT * BSZ;           // 25216

// Workspace layout (bytes). Region A is reused: kp -> vp -> xo (strictly ordered).
constexpr size_t OFF_QP   = 256;
constexpr size_t SZ_QP    = (size_t)M_Q  * EMB * 4;      // 39,321,600
constexpr size_t OFF_A    = OFF_QP + SZ_QP;
constexpr size_t SZ_A     = (size_t)M_KV * EMB * 4;      // 77,463,552
constexpr size_t OFF_QINV = OFF_A + SZ_A;
constexpr size_t OFF_KINV = OFF_QINV + (size_t)COLS * 4;
constexpr size_t OFF_QMN  = OFF_KINV + (size_t)COLS * 4;
constexpr size_t OFF_XMN  = OFF_QMN + (size_t)NT * 128 * 4;
constexpr size_t OFF_G    = OFF_XMN + (size_t)NT * 128 * 4;
constexpr size_t OFF_W    = OFF_G + (size_t)COLS * 128 * 4;
// end = OFF_W + COLS*128*4  ~ 208 MB

// ---------- dtype helpers ----------
__device__ __forceinline__ float dl(const float* p) { return *p; }
__device__ __forceinline__ float dl(const __hip_bfloat16* p) { return __bfloat162float(*p); }
__device__ __forceinline__ void dstore(float* p, float v) { *p = v; }
__device__ __forceinline__ void dstore(__hip_bfloat16* p, float v) { *p = __float2bfloat16(v); }

// ---------- dtype detect: temperature == ones. bf16 1.0 -> first ushort 0x3F80; f32 1.0 -> 0x0000 ----------
__global__ void k_detect(const unsigned short* t16, int* flag) {
    *flag = (t16[0] == 0x3F80u) ? 1 : 0;
}

__global__ void k_zero(float* p, int n) {
    int i = blockIdx.x * 256 + threadIdx.x;
    if (i < n) p[i] = 0.f;
}

// ---------- mapper row-normalize: q_mapper [NT][NQ] -> qmn [NT][128] (pad cols zeroed beforehand) ----------
template <typename T>
__global__ __launch_bounds__(128) void k_qmn(const int* flag, int want, const T* qm, float* dst) {
    if (*flag != want) return;
    __shared__ float red[128];
    int t = blockIdx.x, q = threadIdx.x;
    float v = (q < NQ) ? dl(&qm[t * NQ + q]) : 0.f;
    red[q] = v * v;
    __syncthreads();
    for (int s = 64; s > 0; s >>= 1) { if (q < s) red[q] += red[q + s]; __syncthreads(); }
    float inv = 1.f / fmaxf(sqrtf(red[0]), 1e-12f);
    if (q < NQ) dst[t * 128 + q] = v * inv;
}

// ---------- x_mapper [NQ][NT] row-normalized, stored transposed -> xmn [NT][128] ----------
template <typename T>
__global__ __launch_bounds__(256) void k_xmn(const int* flag, int want, const T* xm, float* dst) {
    if (*flag != want) return;
    __shared__ float red[256];
    int q = blockIdx.x, t = threadIdx.x;
    float v = (t < NT) ? dl(&xm[q * NT + t]) : 0.f;
    red[t] = v * v;
    __syncthreads();
    for (int s = 128; s > 0; s >>= 1) { if (t < s) red[t] += red[t + s]; __syncthreads(); }
    float inv = 1.f / fmaxf(sqrtf(red[0]), 1e-12f);
    if (t < NT) dst[t * 128 + q] = v * inv;
}

// ---------- per-(b, e') inverse L2 norm over tokens: src [ntok][COLS] ----------
__global__ __launch_bounds__(256) void k_colnorm(const float* __restrict__ src, float* __restrict__ dst, int ntok) {
    int col = blockIdx.x * 256 + threadIdx.x;  // 0..COLS-1
    float ss = 0.f;
    for (int n = 0; n < ntok; ++n) {
        float v = src[(size_t)n * COLS + col];
        ss = fmaf(v, v, ss);
    }
    dst[col] = 1.f / fmaxf(sqrtf(ss), 1e-12f);
}

// ---------- generic tiled GEMM: C[M][N] = A.B (+bias[n] | *rowscale[m]) ----------
// A_T=false: A[m*lda+k]; A_T=true: A[k*lda+m].  B_KN=false: B[n*ldb+k]; B_KN=true: B[k*ldb+n].
// EPI: 0 none, 1 +bias[n], 2 *rowscale[m]. M,N must be multiples of 64; K arbitrary.
template <typename TA, typename TB, typename TC, bool A_T, bool B_KN, int EPI>
__global__ __launch_bounds__(256) void k_gemm(const int* flag, int want,
        const TA* __restrict__ A, int lda, const TB* __restrict__ Bm, int ldb,
        TC* __restrict__ C, int ldc, int M, int N, int K,
        const TB* __restrict__ bias, const float* __restrict__ rsc) {
    if (want >= 0 && *flag != want) return;
    __shared__ __align__(16) float As[16][68];
    __shared__ __align__(16) float Bs[16][68];
    const int tid = threadIdx.x;
    const int n0 = blockIdx.x * 64, m0 = blockIdx.y * 64;
    const int tx = tid & 15, ty = tid >> 4;
    float acc[4][4] = {};
    for (int k0 = 0; k0 < K; k0 += 16) {
        if (A_T) {
            int mm = tid & 63, kb = tid >> 6;
#pragma unroll
            for (int r = 0; r < 4; ++r) {
                int kk = kb * 4 + r;
                As[kk][mm] = (k0 + kk < K) ? dl(&A[(size_t)(k0 + kk) * lda + m0 + mm]) : 0.f;
            }
        } else {
            int kk = tid & 15, mb = tid >> 4;
#pragma unroll
            for (int r = 0; r < 4; ++r) {
                int mm = mb * 4 + r;
                As[kk][mm] = (k0 + kk < K) ? dl(&A[(size_t)(m0 + mm) * lda + k0 + kk]) : 0.f;
            }
        }
        if (B_KN) {
            int nn = tid & 63, kb = tid >> 6;
#pragma unroll
            for (int r = 0; r < 4; ++r) {
                int kk = kb * 4 + r;
                Bs[kk][nn] = (k0 + kk < K) ? dl(&Bm[(size_t)(k0 + kk) * ldb + n0 + nn]) : 0.f;
            }
        } else {
            int kk = tid & 15, nb = tid >> 4;
#pragma unroll
            for (int r = 0; r < 4; ++r) {
                int nn = nb * 4 + r;
                Bs[kk][nn] = (k0 + kk < K) ? dl(&Bm[(size_t)(n0 + nn) * ldb + k0 + kk]) : 0.f;
            }
        }
        __syncthreads();
#pragma unroll
        for (int kk = 0; kk < 16; ++kk) {
            float4 a4 = *(const float4*)&As[kk][ty * 4];
            float4 b4 = *(const float4*)&Bs[kk][tx * 4];
            float av[4] = {a4.x, a4.y, a4.z, a4.w};
            float bv[4] = {b4.x, b4.y, b4.z, b4.w};
#pragma unroll
            for (int i = 0; i < 4; ++i)
#pragma unroll
                for (int j = 0; j < 4; ++j) acc[i][j] = fmaf(av[i], bv[j], acc[i][j]);
        }
        __syncthreads();
    }
#pragma unroll
    for (int i = 0; i < 4; ++i) {
        int m = m0 + ty * 4 + i;
        float rs = (EPI == 2) ? rsc[m] : 1.f;
#pragma unroll
        for (int j = 0; j < 4; ++j) {
            int n = n0 + tx * 4 + j;
            float v = acc[i][j];
            if (EPI == 1) v += dl(&bias[n]);
            v *= rs;
            dstore(&C[(size_t)m * ldc + n], v);
        }
    }
}

// ---------- per-(b,h) attention: attn = qn.g^T * temp -> softmax -> out = P.w -> xo ----------
template <typename T>
__global__ __launch_bounds__(256) void k_attn(const int* flag, int want,
        const float* __restrict__ qp, const float* __restrict__ qinv,
        const float* __restrict__ g, const float* __restrict__ w,
        const T* __restrict__ temp, float* __restrict__ xo) {
    if (*flag != want) return;
    const int h = blockIdx.x, b = blockIdx.y;
    const int tid = threadIdx.x;
    const int tx = tid & 15, ty = tid >> 4;
    const int d0 = ty * 4, e0 = tx * 4;
    const int colbase = b * EMB + h * HDD;
    __shared__ __align__(16) float smem[13600];
    float* qn_s = smem;          // [100][68]  (q-major, k-major for the dot)
    float* g_s  = smem + 6800;   // [100][68]

    for (int i = tid; i < NQ * HDD; i += 256) {
        int q = i >> 6, d = i & 63;
        qn_s[q * 68 + d] = qp[(size_t)(q * BSZ + b) * EMB + h * HDD + d] * qinv[colbase + d];
    }
    for (int i = tid; i < HDD * 128; i += 256) {
        int e = i >> 7, q = i & 127;
        float v = g[(size_t)(colbase + e) * 128 + q];
        if (q < NQ) g_s[q * 68 + e] = v;
    }
    __syncthreads();

    float acc[4][4] = {};
#pragma unroll 4
    for (int q = 0; q < NQ; ++q) {
        float4 a4 = *(const float4*)&qn_s[q * 68 + d0];
        float4 b4 = *(const float4*)&g_s[q * 68 + e0];
        float av[4] = {a4.x, a4.y, a4.z, a4.w};
        float bv[4] = {b4.x, b4.y, b4.z, b4.w};
#pragma unroll
        for (int i = 0; i < 4; ++i)
#pragma unroll
            for (int j = 0; j < 4; ++j) acc[i][j] = fmaf(av[i], bv[j], acc[i][j]);
    }
    float tv = dl(&temp[h]);
    __syncthreads();  // done reading qn_s/g_s; regions are reused below

    float* p_s = smem;          // [64 e][68]: p_s[e*68+d]  (transposed for out phase)
    float* w_s = smem + 6800;   // [64 e][104]
#pragma unroll
    for (int j = 0; j < 4; ++j)
#pragma unroll
        for (int i = 0; i < 4; ++i)
            p_s[(e0 + j) * 68 + d0 + i] = acc[i][j] * tv;
    for (int i = tid; i < HDD * 128; i += 256) {
        int e = i >> 7, q = i & 127;
        float v = w[(size_t)(colbase + e) * 128 + q];
        if (q < 104) w_s[e * 104 + q] = v;
    }
    __syncthreads();

    if (tid < 64) {
        int d = tid;
        float mx = -1e30f;
        for (int e = 0; e < 64; ++e) mx = fmaxf(mx, p_s[e * 68 + d]);
        float s = 0.f;
        for (int e = 0; e < 64; ++e) {
            float p = __expf(p_s[e * 68 + d] - mx);
            s += p;
            p_s[e * 68 + d] = p;
        }
        float r = 1.f / s;
        for (int e = 0; e < 64; ++e) p_s[e * 68 + d] *= r;
    }
    __syncthreads();

#pragma unroll
    for (int pass = 0; pass < 2; ++pass) {
        int q0 = (tx + pass * 16) * 4;
        if (q0 < NQ) {
            float o[4][4] = {};
#pragma unroll 4
            for (int e = 0; e < 64; ++e) {
                float4 a4 = *(const float4*)&p_s[e * 68 + d0];
                float4 w4 = *(const float4*)&w_s[e * 104 + q0];
                float av[4] = {a4.x, a4.y, a4.z, a4.w};
                float wv[4] = {w4.x, w4.y, w4.z, w4.w};
#pragma unroll
                for (int i = 0; i < 4; ++i)
#pragma unroll
                    for (int j = 0; j < 4; ++j) o[i][j] = fmaf(av[i], wv[j], o[i][j]);
            }
#pragma unroll
            for (int j = 0; j < 4; ++j) {
                int q = q0 + j;
                float4 val = make_float4(o[0][j], o[1][j], o[2][j], o[3][j]);
                *(float4*)&xo[(size_t)(q * BSZ + b) * EMB + h * HDD + d0] = val;
            }
        }
    }
}

using bf16 = __hip_bfloat16;

extern "C" void kernel_launch(void* const* d_in, const int* in_sizes, int n_in,
                              void* d_out, int out_size, void* d_ws, size_t ws_size,
                              hipStream_t stream) {
    char* ws = (char*)d_ws;
    int* flag    = (int*)ws;
    float* qp    = (float*)(ws + OFF_QP);
    float* ab    = (float*)(ws + OFF_A);    // kp -> vp -> xo (ordered reuse)
    float* qinv  = (float*)(ws + OFF_QINV);
    float* kinv  = (float*)(ws + OFF_KINV);
    float* qmn   = (float*)(ws + OFF_QMN);
    float* xmn   = (float*)(ws + OFF_XMN);
    float* gb    = (float*)(ws + OFF_G);
    float* wb    = (float*)(ws + OFF_W);

    k_detect<<<1, 1, 0, stream>>>((const unsigned short*)d_in[7], flag);
    k_zero<<<197, 256, 0, stream>>>(qmn, 2 * NT * 128);  // qmn+xmn contiguous

    // mapper normalizations (both dtype variants; wrong one exits)
    k_qmn<float><<<197, 128, 0, stream>>>(flag, 0, (const float*)d_in[8], qmn);
    k_qmn<bf16 ><<<197, 128, 0, stream>>>(flag, 1, (const bf16*)d_in[8], qmn);
    k_xmn<float><<<100, 256, 0, stream>>>(flag, 0, (const float*)d_in[9], xmn);
    k_xmn<bf16 ><<<100, 256, 0, stream>>>(flag, 1, (const bf16*)d_in[9], xmn);

    // proj-k: kp = key @ wk^T + bk   -> region A
    {
        dim3 grd(12, M_KV / 64);
        k_gemm<float, float, float, false, false, 1><<<grd, 256, 0, stream>>>(flag, 0,
            (const float*)d_in[1], EMB, (const float*)d_in[3] + EMB * EMB, EMB, ab, EMB,
            M_KV, EMB, EMB, (const float*)d_in[4] + EMB, nullptr);
        k_gemm<bf16, bf16, float, false, false, 1><<<grd, 256, 0, stream>>>(flag, 1,
            (const bf16*)d_in[1], EMB, (const bf16*)d_in[3] + EMB * EMB, EMB, ab, EMB,
            M_KV, EMB, EMB, (const bf16*)d_in[4] + EMB, nullptr);
    }
    k_colnorm<<<COLS / 256, 256, 0, stream>>>(ab, kinv, NT);
    // g = kp^T @ qmn, row-scaled by kinv  [COLS][128]
    k_gemm<float, float, float, true, true, 2><<<dim3(2, COLS / 64), 256, 0, stream>>>(flag, -1,
        ab, COLS, qmn, 128, gb, 128, COLS, 128, NT, nullptr, kinv);

    // proj-v: vp -> region A (kp dead after g)
    {
        dim3 grd(12, M_KV / 64);
        k_gemm<float, float, float, false, false, 1><<<grd, 256, 0, stream>>>(flag, 0,
            (const float*)d_in[2], EMB, (const float*)d_in[3] + 2 * EMB * EMB, EMB, ab, EMB,
            M_KV, EMB, EMB, (const float*)d_in[4] + 2 * EMB, nullptr);
        k_gemm<bf16, bf16, float, false, false, 1><<<grd, 256, 0, stream>>>(flag, 1,
            (const bf16*)d_in[2], EMB, (const bf16*)d_in[3] + 2 * EMB * EMB, EMB, ab, EMB,
            M_KV, EMB, EMB, (const bf16*)d_in[4] + 2 * EMB, nullptr);
    }
    // w = vp^T @ xmn  [COLS][128]
    k_gemm<float, float, float, true, true, 0><<<dim3(2, COLS / 64), 256, 0, stream>>>(flag, -1,
        ab, COLS, xmn, 128, wb, 128, COLS, 128, NT, nullptr, nullptr);

    // proj-q: qp = query @ wq^T + bq
    {
        dim3 grd(12, M_Q / 64);
        k_gemm<float, float, float, false, false, 1><<<grd, 256, 0, stream>>>(flag, 0,
            (const float*)d_in[0], EMB, (const float*)d_in[3], EMB, qp, EMB,
            M_Q, EMB, EMB, (const float*)d_in[4], nullptr);
        k_gemm<bf16, bf16, float, false, false, 1><<<grd, 256, 0, stream>>>(flag, 1,
            (const bf16*)d_in[0], EMB, (const bf16*)d_in[3], EMB, qp, EMB,
            M_Q, EMB, EMB, (const bf16*)d_in[4], nullptr);
    }
    k_colnorm<<<COLS / 256, 256, 0, stream>>>(qp, qinv, NQ);

    // middle attention -> xo in region A (vp dead after w)
    k_attn<float><<<dim3(NHD, BSZ), 256, 0, stream>>>(flag, 0, qp, qinv, gb, wb, (const float*)d_in[7], ab);
    k_attn<bf16 ><<<dim3(NHD, BSZ), 256, 0, stream>>>(flag, 1, qp, qinv, gb, wb, (const bf16*)d_in[7], ab);

    // out-proj: out = xo @ wout^T + bout
    {
        dim3 grd(12, M_Q / 64);
        k_gemm<float, float, float, false, false, 1><<<grd, 256, 0, stream>>>(flag, 0,
            ab, EMB, (const float*)d_in[5], EMB, (float*)d_out, EMB,
            M_Q, EMB, EMB, (const float*)d_in[6], nullptr);
        k_gemm<float, bf16, bf16, false, false, 1><<<grd, 256, 0, stream>>>(flag, 1,
            ab, EMB, (const bf16*)d_in[5], EMB, (bf16*)d_out, EMB,
            M_Q, EMB, EMB, (const bf16*)d_in[6], nullptr);
    }
}

// Round 5
// 863.565 us; speedup vs baseline: 2.2383x; 2.2383x over previous
//
#include <hip/hip_runtime.h>
#include <hip/hip_bf16.h>

using bf16 = __hip_bfloat16;

// Problem constants
constexpr int NQ  = 100;
constexpr int NT  = 197;
constexpr int BSZ = 128;
constexpr int EMB = 768;
constexpr int NHD = 12;
constexpr int HDD = 64;
constexpr int COLS = BSZ * EMB;          // 98304
constexpr int M_Q  = NQ * BSZ;           // 12800  = 100*128
constexpr int M_KV = NT * BSZ;           // 25216  = 197*128

// Workspace layout: IDENTICAL to round 1's proven 218.4 MB footprint.
// Region A reuse (strictly ordered): kp(f32) -> vp(f32) -> xo(f32, 39.3MB <= 77.5MB).
// NO bf16 tensor copies exist — f32->bf16 happens inside MFMA staging.
constexpr size_t OFF_QP   = 256;
constexpr size_t SZ_QP    = (size_t)M_Q  * EMB * 4;      // 39,321,600
constexpr size_t OFF_A    = OFF_QP + SZ_QP;
constexpr size_t SZ_A     = (size_t)M_KV * EMB * 4;      // 77,463,552
constexpr size_t OFF_QINV = OFF_A + SZ_A;
constexpr size_t OFF_KINV = OFF_QINV + (size_t)COLS * 4;
constexpr size_t OFF_QMN  = OFF_KINV + (size_t)COLS * 4;
constexpr size_t OFF_XMN  = OFF_QMN + (size_t)NT * 128 * 4;
constexpr size_t OFF_G    = OFF_XMN + (size_t)NT * 128 * 4;
constexpr size_t OFF_W    = OFF_G + (size_t)COLS * 128 * 4;
// end = OFF_W + COLS*128*4 = 218,436,864 (== round-1 footprint, known to fit)

__device__ __forceinline__ float dl(const float* p) { return *p; }
__device__ __forceinline__ float dl(const bf16* p) { return __bfloat162float(*p); }

__device__ __forceinline__ ushort f2bf(float x) {
    union { float f; unsigned u; } v; v.f = x;
    unsigned r = v.u + 0x7FFFu + ((v.u >> 16) & 1u);   // RNE
    return (ushort)(r >> 16);
}
__device__ __forceinline__ void dstore(float* p, float v) { *p = v; }
__device__ __forceinline__ void dstore(bf16* p, float v) { *p = __float2bfloat16(v); }

typedef __attribute__((ext_vector_type(8))) short short8;
typedef __attribute__((ext_vector_type(4))) float f32x4;

// 8-element load -> bf16 fragment; converts in-register when source is f32.
__device__ __forceinline__ short8 ld8(const bf16* p) { return *(const short8*)p; }
__device__ __forceinline__ short8 ld8(const float* p) {
    float4 a = *(const float4*)p, b = *(const float4*)(p + 4);
    short8 r;
    r[0] = (short)f2bf(a.x); r[1] = (short)f2bf(a.y); r[2] = (short)f2bf(a.z); r[3] = (short)f2bf(a.w);
    r[4] = (short)f2bf(b.x); r[5] = (short)f2bf(b.y); r[6] = (short)f2bf(b.z); r[7] = (short)f2bf(b.w);
    return r;
}

// ---------- dtype detect: temperature == ones. bf16 1.0 -> ushort[0]=0x3F80; f32 1.0 -> 0x0000 ----------
__global__ void k_detect(const unsigned short* t16, int* flag) {
    *flag = (t16[0] == 0x3F80u) ? 1 : 0;
}

__global__ void k_zero(float* p, int n) {
    int i = blockIdx.x * 256 + threadIdx.x;
    if (i < n) p[i] = 0.f;
}

// ---------- q_mapper [NT][NQ] row-normalized -> qmn [NT][128] (pad zeroed by k_zero) ----------
template <typename T>
__global__ __launch_bounds__(128) void k_qmn(const int* flag, int want, const T* qm, float* dst) {
    if (*flag != want) return;
    __shared__ float red[128];
    int t = blockIdx.x, q = threadIdx.x;
    float v = (q < NQ) ? dl(&qm[t * NQ + q]) : 0.f;
    red[q] = v * v;
    __syncthreads();
    for (int s = 64; s > 0; s >>= 1) { if (q < s) red[q] += red[q + s]; __syncthreads(); }
    float inv = 1.f / fmaxf(sqrtf(red[0]), 1e-12f);
    if (q < NQ) dst[t * 128 + q] = v * inv;
}

// ---------- x_mapper [NQ][NT] row-normalized, stored transposed -> xmn [NT][128] ----------
template <typename T>
__global__ __launch_bounds__(256) void k_xmn(const int* flag, int want, const T* xm, float* dst) {
    if (*flag != want) return;
    __shared__ float red[256];
    int q = blockIdx.x, t = threadIdx.x;
    float v = (t < NT) ? dl(&xm[q * NT + t]) : 0.f;
    red[t] = v * v;
    __syncthreads();
    for (int s = 128; s > 0; s >>= 1) { if (t < s) red[t] += red[t + s]; __syncthreads(); }
    float inv = 1.f / fmaxf(sqrtf(red[0]), 1e-12f);
    if (t < NT) dst[t * 128 + q] = v * inv;
}

// ---------- per-(b, e') inverse L2 norm over tokens: src [ntok][COLS] ----------
__global__ __launch_bounds__(256) void k_colnorm(const float* __restrict__ src, float* __restrict__ dst, int ntok) {
    int col = blockIdx.x * 256 + threadIdx.x;
    float ss = 0.f;
    for (int n = 0; n < ntok; ++n) {
        float v = src[(size_t)n * COLS + col];
        ss = fmaf(v, v, ss);
    }
    dst[col] = 1.f / fmaxf(sqrtf(ss), 1e-12f);
}

// ---------- MFMA bf16 GEMM with fused f32->bf16 staging ----------
// C[M][N] = bf16(A[M][K]) . bf16(W[N][K])^T + bias[n]
// 128x128 tile, 4 waves (2x2 of 64x64), 4x4 16x16x32 MFMA frags, short8 LDS staging.
// M%128==0, N%128==0, K%32==0. Source dtypes TA/TB are float or bf16 (converted at stage time).
template <typename TA, typename TB, typename TC>
__global__ __launch_bounds__(256) void k_gemm_mfma(const int* flag, int want,
        const TA* __restrict__ Ab, const TB* __restrict__ Wb,
        TC* __restrict__ C, const TB* __restrict__ bias, int M, int N, int K) {
    if (*flag != want) return;
    __shared__ __align__(16) ushort As[128 * 32];
    __shared__ __align__(16) ushort Bs[128 * 32];
    const int t = threadIdx.x;
    const int n0 = blockIdx.x * 128, m0 = blockIdx.y * 128;
    const int ln = t & 63, wv = t >> 6;
    const int ln15 = ln & 15, q8 = ln >> 4;
    const int mw = (wv & 1) * 64, nw = (wv >> 1) * 64;

    // staging: thread t covers tile elem (t>>2, (t&3)*8); LDS [128 rows][32 k] (rows 64.. at +2048)
    const int srow = t >> 2, skk = (t & 3) * 8;
    const TA* gA = Ab + (size_t)(m0 + srow) * K + skk;
    const TB* gB = Wb + (size_t)(n0 + srow) * K + skk;
    const size_t rstep = (size_t)64 * K;

    f32x4 acc[4][4] = {};
    for (int k0 = 0; k0 < K; k0 += 32) {
        short8 ra0 = ld8(gA + k0);
        short8 ra1 = ld8(gA + rstep + k0);
        short8 rb0 = ld8(gB + k0);
        short8 rb1 = ld8(gB + rstep + k0);
        *(short8*)&As[t * 8]        = ra0;
        *(short8*)&As[2048 + t * 8] = ra1;
        *(short8*)&Bs[t * 8]        = rb0;
        *(short8*)&Bs[2048 + t * 8] = rb1;
        __syncthreads();
        short8 a[4], b[4];
#pragma unroll
        for (int i = 0; i < 4; ++i)
            a[i] = *(const short8*)&As[(mw + i * 16 + ln15) * 32 + q8 * 8];
#pragma unroll
        for (int j = 0; j < 4; ++j)
            b[j] = *(const short8*)&Bs[(nw + j * 16 + ln15) * 32 + q8 * 8];
#pragma unroll
        for (int i = 0; i < 4; ++i)
#pragma unroll
            for (int j = 0; j < 4; ++j)
                acc[i][j] = __builtin_amdgcn_mfma_f32_16x16x32_bf16(a[i], b[j], acc[i][j], 0, 0, 0);
        __syncthreads();
    }
    // C/D layout: col = lane&15 (n), row = (lane>>4)*4 + reg (m)  [learn_hip m89/m91]
#pragma unroll
    for (int j = 0; j < 4; ++j) {
        const int n = n0 + nw + j * 16 + ln15;
        const float bv = dl(&bias[n]);
#pragma unroll
        for (int i = 0; i < 4; ++i) {
            const int mb = m0 + mw + i * 16 + q8 * 4;
#pragma unroll
            for (int r = 0; r < 4; ++r)
                dstore(&C[(size_t)(mb + r) * N + n], acc[i][j][r] + bv);
        }
    }
}

// ---------- f32 tiled GEMM (A transposed, B [K][N]) for the mapper contractions ----------
// C[M][N] = A^T.B, A[k*lda+m]. EPI: 0 none, 2 *rowscale[m]. M,N mult of 64. (round-1 proven)
template <int EPI>
__global__ __launch_bounds__(256) void k_gemm_t(
        const float* __restrict__ A, int lda, const float* __restrict__ Bm, int ldb,
        float* __restrict__ C, int ldc, int M, int N, int K, const float* __restrict__ rsc) {
    __shared__ __align__(16) float As[16][68];
    __shared__ __align__(16) float Bs[16][68];
    const int tid = threadIdx.x;
    const int n0 = blockIdx.x * 64, m0 = blockIdx.y * 64;
    const int tx = tid & 15, ty = tid >> 4;
    float acc[4][4] = {};
    for (int k0 = 0; k0 < K; k0 += 16) {
        {
            int mm = tid & 63, kb = tid >> 6;
#pragma unroll
            for (int r = 0; r < 4; ++r) {
                int kk = kb * 4 + r;
                As[kk][mm] = (k0 + kk < K) ? A[(size_t)(k0 + kk) * lda + m0 + mm] : 0.f;
            }
            int nn = tid & 63;
#pragma unroll
            for (int r = 0; r < 4; ++r) {
                int kk = kb * 4 + r;
                Bs[kk][nn] = (k0 + kk < K) ? Bm[(size_t)(k0 + kk) * ldb + n0 + nn] : 0.f;
            }
        }
        __syncthreads();
#pragma unroll
        for (int kk = 0; kk < 16; ++kk) {
            float4 a4 = *(const float4*)&As[kk][ty * 4];
            float4 b4 = *(const float4*)&Bs[kk][tx * 4];
            float av[4] = {a4.x, a4.y, a4.z, a4.w};
            float bv[4] = {b4.x, b4.y, b4.z, b4.w};
#pragma unroll
            for (int i = 0; i < 4; ++i)
#pragma unroll
                for (int j = 0; j < 4; ++j) acc[i][j] = fmaf(av[i], bv[j], acc[i][j]);
        }
        __syncthreads();
    }
#pragma unroll
    for (int i = 0; i < 4; ++i) {
        int m = m0 + ty * 4 + i;
        float rs = (EPI == 2) ? rsc[m] : 1.f;
#pragma unroll
        for (int j = 0; j < 4; ++j)
            C[(size_t)m * ldc + n0 + tx * 4 + j] = acc[i][j] * rs;
    }
}

// ---------- per-(b,h) attention (round-1 proven, f32 xo out) ----------
template <typename T>
__global__ __launch_bounds__(256) void k_attn(const int* flag, int want,
        const float* __restrict__ qp, const float* __restrict__ qinv,
        const float* __restrict__ g, const float* __restrict__ w,
        const T* __restrict__ temp, float* __restrict__ xo) {
    if (*flag != want) return;
    const int h = blockIdx.x, b = blockIdx.y;
    const int tid = threadIdx.x;
    const int tx = tid & 15, ty = tid >> 4;
    const int d0 = ty * 4, e0 = tx * 4;
    const int colbase = b * EMB + h * HDD;
    __shared__ __align__(16) float smem[13600];
    float* qn_s = smem;          // [100][68]
    float* g_s  = smem + 6800;   // [100][68]

    for (int i = tid; i < NQ * HDD; i += 256) {
        int q = i >> 6, d = i & 63;
        qn_s[q * 68 + d] = qp[(size_t)(q * BSZ + b) * EMB + h * HDD + d] * qinv[colbase + d];
    }
    for (int i = tid; i < HDD * 128; i += 256) {
        int e = i >> 7, q = i & 127;
        float v = g[(size_t)(colbase + e) * 128 + q];
        if (q < NQ) g_s[q * 68 + e] = v;
    }
    __syncthreads();

    float acc[4][4] = {};
#pragma unroll 4
    for (int q = 0; q < NQ; ++q) {
        float4 a4 = *(const float4*)&qn_s[q * 68 + d0];
        float4 b4 = *(const float4*)&g_s[q * 68 + e0];
        float av[4] = {a4.x, a4.y, a4.z, a4.w};
        float bv[4] = {b4.x, b4.y, b4.z, b4.w};
#pragma unroll
        for (int i = 0; i < 4; ++i)
#pragma unroll
            for (int j = 0; j < 4; ++j) acc[i][j] = fmaf(av[i], bv[j], acc[i][j]);
    }
    float tv = dl(&temp[h]);
    __syncthreads();

    float* p_s = smem;          // [64 e][68]
    float* w_s = smem + 6800;   // [64 e][104]
#pragma unroll
    for (int j = 0; j < 4; ++j)
#pragma unroll
        for (int i = 0; i < 4; ++i)
            p_s[(e0 + j) * 68 + d0 + i] = acc[i][j] * tv;
    for (int i = tid; i < HDD * 128; i += 256) {
        int e = i >> 7, q = i & 127;
        float v = w[(size_t)(colbase + e) * 128 + q];
        if (q < 104) w_s[e * 104 + q] = v;
    }
    __syncthreads();

    if (tid < 64) {
        int d = tid;
        float mx = -1e30f;
        for (int e = 0; e < 64; ++e) mx = fmaxf(mx, p_s[e * 68 + d]);
        float s = 0.f;
        for (int e = 0; e < 64; ++e) {
            float p = __expf(p_s[e * 68 + d] - mx);
            s += p;
            p_s[e * 68 + d] = p;
        }
        float r = 1.f / s;
        for (int e = 0; e < 64; ++e) p_s[e * 68 + d] *= r;
    }
    __syncthreads();

#pragma unroll
    for (int pass = 0; pass < 2; ++pass) {
        int q0 = (tx + pass * 16) * 4;
        if (q0 < NQ) {
            float o[4][4] = {};
#pragma unroll 4
            for (int e = 0; e < 64; ++e) {
                float4 a4 = *(const float4*)&p_s[e * 68 + d0];
                float4 w4 = *(const float4*)&w_s[e * 104 + q0];
                float av[4] = {a4.x, a4.y, a4.z, a4.w};
                float wv[4] = {w4.x, w4.y, w4.z, w4.w};
#pragma unroll
                for (int i = 0; i < 4; ++i)
#pragma unroll
                    for (int j = 0; j < 4; ++j) o[i][j] = fmaf(av[i], wv[j], o[i][j]);
            }
#pragma unroll
            for (int j = 0; j < 4; ++j) {
                int q = q0 + j;
                float4 val = make_float4(o[0][j], o[1][j], o[2][j], o[3][j]);
                *(float4*)&xo[(size_t)(q * BSZ + b) * EMB + h * HDD + d0] = val;
            }
        }
    }
}

extern "C" void kernel_launch(void* const* d_in, const int* in_sizes, int n_in,
                              void* d_out, int out_size, void* d_ws, size_t ws_size,
                              hipStream_t stream) {
    char* ws = (char*)d_ws;
    int*    flag = (int*)ws;
    float*  qp   = (float*)(ws + OFF_QP);
    float*  abf  = (float*)(ws + OFF_A);    // kp -> vp -> xo (all f32, ordered reuse)
    float*  qinv = (float*)(ws + OFF_QINV);
    float*  kinv = (float*)(ws + OFF_KINV);
    float*  qmn  = (float*)(ws + OFF_QMN);
    float*  xmn  = (float*)(ws + OFF_XMN);
    float*  gb   = (float*)(ws + OFF_G);
    float*  wb   = (float*)(ws + OFF_W);

    k_detect<<<1, 1, 0, stream>>>((const unsigned short*)d_in[7], flag);
    k_zero<<<197, 256, 0, stream>>>(qmn, 2 * NT * 128);  // qmn+xmn contiguous

    // mapper normalizations (dtype-hedged)
    k_qmn<float><<<197, 128, 0, stream>>>(flag, 0, (const float*)d_in[8], qmn);
    k_qmn<bf16 ><<<197, 128, 0, stream>>>(flag, 1, (const bf16*)d_in[8], qmn);
    k_xmn<float><<<100, 256, 0, stream>>>(flag, 0, (const float*)d_in[9], xmn);
    k_xmn<bf16 ><<<100, 256, 0, stream>>>(flag, 1, (const bf16*)d_in[9], xmn);

    // kp = key @ wk^T + bk  (MFMA, fused cvt)
    k_gemm_mfma<float, float, float><<<dim3(6, 197), 256, 0, stream>>>(flag, 0,
        (const float*)d_in[1], (const float*)d_in[3] + (size_t)EMB * EMB, abf,
        (const float*)d_in[4] + EMB, M_KV, EMB, EMB);
    k_gemm_mfma<bf16, bf16, float><<<dim3(6, 197), 256, 0, stream>>>(flag, 1,
        (const bf16*)d_in[1], (const bf16*)d_in[3] + (size_t)EMB * EMB, abf,
        (const bf16*)d_in[4] + EMB, M_KV, EMB, EMB);
    k_colnorm<<<COLS / 256, 256, 0, stream>>>(abf, kinv, NT);
    // g = kp^T @ qmn, row-scaled by kinv
    k_gemm_t<2><<<dim3(2, COLS / 64), 256, 0, stream>>>(
        abf, COLS, qmn, 128, gb, 128, COLS, 128, NT, kinv);

    // vp = value @ wv^T + bv  (MFMA) — kp dead
    k_gemm_mfma<float, float, float><<<dim3(6, 197), 256, 0, stream>>>(flag, 0,
        (const float*)d_in[2], (const float*)d_in[3] + (size_t)2 * EMB * EMB, abf,
        (const float*)d_in[4] + 2 * EMB, M_KV, EMB, EMB);
    k_gemm_mfma<bf16, bf16, float><<<dim3(6, 197), 256, 0, stream>>>(flag, 1,
        (const bf16*)d_in[2], (const bf16*)d_in[3] + (size_t)2 * EMB * EMB, abf,
        (const bf16*)d_in[4] + 2 * EMB, M_KV, EMB, EMB);
    // w = vp^T @ xmn
    k_gemm_t<0><<<dim3(2, COLS / 64), 256, 0, stream>>>(
        abf, COLS, xmn, 128, wb, 128, COLS, 128, NT, nullptr);

    // qp = query @ wq^T + bq  (MFMA)
    k_gemm_mfma<float, float, float><<<dim3(6, 100), 256, 0, stream>>>(flag, 0,
        (const float*)d_in[0], (const float*)d_in[3], qp, (const float*)d_in[4], M_Q, EMB, EMB);
    k_gemm_mfma<bf16, bf16, float><<<dim3(6, 100), 256, 0, stream>>>(flag, 1,
        (const bf16*)d_in[0], (const bf16*)d_in[3], qp, (const bf16*)d_in[4], M_Q, EMB, EMB);
    k_colnorm<<<COLS / 256, 256, 0, stream>>>(qp, qinv, NQ);

    // attention -> xo (f32, region A; vp dead)
    k_attn<float><<<dim3(NHD, BSZ), 256, 0, stream>>>(flag, 0, qp, qinv, gb, wb, (const float*)d_in[7], abf);
    k_attn<bf16 ><<<dim3(NHD, BSZ), 256, 0, stream>>>(flag, 1, qp, qinv, gb, wb, (const bf16*)d_in[7], abf);

    // out = xo @ wout^T + bout  (MFMA, fused cvt of xo; C dtype per flag)
    k_gemm_mfma<float, float, float><<<dim3(6, 100), 256, 0, stream>>>(flag, 0,
        abf, (const float*)d_in[5], (float*)d_out, (const float*)d_in[6], M_Q, EMB, EMB);
    k_gemm_mfma<float, bf16, bf16><<<dim3(6, 100), 256, 0, stream>>>(flag, 1,
        abf, (const bf16*)d_in[5], (bf16*)d_out, (const bf16*)d_in[6], M_Q, EMB, EMB);
}